// Round 6
// baseline (16.402 us; speedup 1.0000x reference)
//
#include <hip/hip_runtime.h>
#include <math.h>

#define HID 5
#define NTAB 27

// LDS weight-staging layout (flat float offsets)
#define OFF_WIH1 0     // 60
#define OFF_WHH1 60    // 100
#define OFF_BIH1 160   // 20
#define OFF_BHH1 180   // 20
#define OFF_WIH2 200   // 100
#define OFF_WHH2 300   // 100
#define OFF_BIH2 400   // 20
#define OFF_BHH2 420   // 20
#define OFF_WOUT 440   // 5
#define OFF_BOUT 445   // 1
#define OFF_H10  446   // 5
#define OFF_C10  451   // 5
#define OFF_H20  456   // 5
#define OFF_C20  461   // 5
#define OFF_POLY 466   // 4
#define NW       470

__device__ __forceinline__ float sigm(float x) { return 1.0f / (1.0f + expf(-x)); }
__device__ __forceinline__ float softplus_f(float x) {
    return fmaxf(x, 0.0f) + log1pf(expf(-fabsf(x)));
}

// ---------------------------------------------------------------------------
// Kernel A: table via cooperative staging — 256 threads pull all 470 weight
// floats in ONE memory-latency round into LDS, then lanes 0..26 compute the
// 27-entry LUT from LDS (pure VALU chain, no global loads on critical path).
// ---------------------------------------------------------------------------
__global__ __launch_bounds__(256) void table_kernel(
    const float* __restrict__ W_ih1, const float* __restrict__ W_hh1,
    const float* __restrict__ b_ih1, const float* __restrict__ b_hh1,
    const float* __restrict__ W_ih2, const float* __restrict__ W_hh2,
    const float* __restrict__ b_ih2, const float* __restrict__ b_hh2,
    const float* __restrict__ W_out, const float* __restrict__ b_out,
    const float* __restrict__ h1_0, const float* __restrict__ c1_0,
    const float* __restrict__ h2_0, const float* __restrict__ c2_0,
    const float* __restrict__ poly, const int* __restrict__ t_ptr,
    float* __restrict__ tab_out)
{
    __shared__ float sw[NW];
    const int tid = threadIdx.x;

    for (int i = tid; i < NW; i += 256) {
        float v;
        if      (i < 60)  v = W_ih1[i];
        else if (i < 160) v = W_hh1[i - 60];
        else if (i < 180) v = b_ih1[i - 160];
        else if (i < 200) v = b_hh1[i - 180];
        else if (i < 300) v = W_ih2[i - 200];
        else if (i < 400) v = W_hh2[i - 300];
        else if (i < 420) v = b_ih2[i - 400];
        else if (i < 440) v = b_hh2[i - 420];
        else if (i < 445) v = W_out[i - 440];
        else if (i < 446) v = b_out[0];
        else if (i < 451) v = h1_0[i - 446];
        else if (i < 456) v = c1_0[i - 451];
        else if (i < 461) v = h2_0[i - 456];
        else if (i < 466) v = c2_0[i - 461];
        else              v = poly[i - 466];
        sw[i] = v;
    }
    __syncthreads();

    if (tid < NTAB) {
        float gn = (float)(tid % 3) - 1.0f;
        float ln = (float)((tid / 3) % 3) - 1.0f;
        float xn = (float)(tid / 9) - 1.0f;

        float h1[HID];
        #pragma unroll
        for (int j = 0; j < HID; ++j) {
            float gk[4];
            #pragma unroll
            for (int q = 0; q < 4; ++q) {
                int k = j + q * HID;
                float acc = sw[OFF_BIH1 + k] + sw[OFF_BHH1 + k];
                #pragma unroll
                for (int m = 0; m < HID; ++m) acc += sw[OFF_WHH1 + k * HID + m] * sw[OFF_H10 + m];
                acc += sw[OFF_WIH1 + k * 3 + 0] * xn
                     + sw[OFF_WIH1 + k * 3 + 1] * ln
                     + sw[OFF_WIH1 + k * 3 + 2] * gn;
                gk[q] = acc;
            }
            float c = sigm(gk[1]) * sw[OFF_C10 + j] + sigm(gk[0]) * tanhf(gk[2]);
            h1[j] = sigm(gk[3]) * tanhf(c);
        }

        float h2v[HID];
        #pragma unroll
        for (int j = 0; j < HID; ++j) {
            float gk[4];
            #pragma unroll
            for (int q = 0; q < 4; ++q) {
                int k = j + q * HID;
                float acc = sw[OFF_BIH2 + k] + sw[OFF_BHH2 + k];
                #pragma unroll
                for (int m = 0; m < HID; ++m) acc += sw[OFF_WHH2 + k * HID + m] * sw[OFF_H20 + m];
                #pragma unroll
                for (int m = 0; m < HID; ++m) acc += sw[OFF_WIH2 + k * HID + m] * h1[m];
                gk[q] = acc;
            }
            float c = sigm(gk[1]) * sw[OFF_C20 + j] + sigm(gk[0]) * tanhf(gk[2]);
            h2v[j] = sigm(gk[3]) * tanhf(c);
        }

        float v = sw[OFF_BOUT];
        #pragma unroll
        for (int m = 0; m < HID; ++m) v += sw[OFF_WOUT + m] * h2v[m];

        int t = *t_ptr;
        float tf = (float)t;
        float pv = 0.0f, p = 1.0f;   // t^0 == 1 even for t==0 (matches Python)
        #pragma unroll
        for (int jj = 0; jj < 4; ++jj) { pv += softplus_f(sw[OFF_POLY + jj]) * p; p *= tf; }
        float gt = exp2f(tf * -0.0144995696951150f);   // 0.99^t

        tab_out[tid] = pv * gt * tanhf(v);
    }
}

// ---------------------------------------------------------------------------
// Kernel B: pure streaming; per-block setup is ONE 27-float parallel load.
// ---------------------------------------------------------------------------
__device__ __forceinline__ float sample_out(const float* __restrict__ tab,
                                            float x, float l, float g) {
    int sx = (x > 0.0f) - (x < 0.0f);
    int sl = (l > 0.0f) - (l < 0.0f);
    int sg = (g > 0.0f) - (g < 0.0f);
    float ax = fabsf(x);
    float scale = (ax > 0.0f) ? ax : 1.0f;
    return tab[(sx + 1) * 9 + (sl + 1) * 3 + (sg + 1)] * scale;
}

__global__ __launch_bounds__(256) void stream_kernel(
    const float* __restrict__ bx, const float* __restrict__ bl,
    const float* __restrict__ bg, const float* __restrict__ tab,
    float* __restrict__ out, int N)
{
    __shared__ float s_table[32];
    const int tid = threadIdx.x;

    const int gtid = blockIdx.x * blockDim.x + tid;
    const int gstride = gridDim.x * blockDim.x;
    const int nvec = N >> 2;

    const float4* bx4 = reinterpret_cast<const float4*>(bx);
    const float4* bl4 = reinterpret_cast<const float4*>(bl);
    const float4* bg4 = reinterpret_cast<const float4*>(bg);
    float4* out4 = reinterpret_cast<float4*>(out);

    // issue streaming loads before the table fetch/barrier
    float4 x0, l0, g0;
    bool have0 = (gtid < nvec);
    if (have0) { x0 = bx4[gtid]; l0 = bl4[gtid]; g0 = bg4[gtid]; }

    if (tid < NTAB) s_table[tid] = tab[tid];
    __syncthreads();

    if (have0) {
        float4 o;
        o.x = sample_out(s_table, x0.x, l0.x, g0.x);
        o.y = sample_out(s_table, x0.y, l0.y, g0.y);
        o.z = sample_out(s_table, x0.z, l0.z, g0.z);
        o.w = sample_out(s_table, x0.w, l0.w, g0.w);
        out4[gtid] = o;
    }
    for (int i = gtid + gstride; i < nvec; i += gstride) {
        float4 x = bx4[i];
        float4 l = bl4[i];
        float4 g = bg4[i];
        float4 o;
        o.x = sample_out(s_table, x.x, l.x, g.x);
        o.y = sample_out(s_table, x.y, l.y, g.y);
        o.z = sample_out(s_table, x.z, l.z, g.z);
        o.w = sample_out(s_table, x.w, l.w, g.w);
        out4[i] = o;
    }
    for (int i = (nvec << 2) + gtid; i < N; i += gstride) {
        out[i] = sample_out(s_table, bx[i], bl[i], bg[i]);
    }
}

extern "C" void kernel_launch(void* const* d_in, const int* in_sizes, int n_in,
                              void* d_out, int out_size, void* d_ws, size_t ws_size,
                              hipStream_t stream) {
    const float* bx    = (const float*)d_in[0];
    const float* bl    = (const float*)d_in[1];
    const float* bg    = (const float*)d_in[2];
    const float* W_ih1 = (const float*)d_in[3];
    const float* W_hh1 = (const float*)d_in[4];
    const float* b_ih1 = (const float*)d_in[5];
    const float* b_hh1 = (const float*)d_in[6];
    const float* W_ih2 = (const float*)d_in[7];
    const float* W_hh2 = (const float*)d_in[8];
    const float* b_ih2 = (const float*)d_in[9];
    const float* b_hh2 = (const float*)d_in[10];
    const float* W_out = (const float*)d_in[11];
    const float* b_out = (const float*)d_in[12];
    const float* h1_0  = (const float*)d_in[13];
    const float* c1_0  = (const float*)d_in[14];
    const float* h2_0  = (const float*)d_in[15];
    const float* c2_0  = (const float*)d_in[16];
    const float* poly  = (const float*)d_in[17];
    const int*   t_ptr = (const int*)d_in[18];
    float* out = (float*)d_out;
    float* tab = (float*)d_ws;   // 27 floats of scratch

    int N = in_sizes[0];
    int nvec = N >> 2;
    int blocks = (nvec + 255) / 256;
    if (blocks < 1) blocks = 1;
    if (blocks > 2048) blocks = 2048;

    table_kernel<<<1, 256, 0, stream>>>(
        W_ih1, W_hh1, b_ih1, b_hh1, W_ih2, W_hh2, b_ih2, b_hh2,
        W_out, b_out, h1_0, c1_0, h2_0, c2_0, poly, t_ptr, tab);

    stream_kernel<<<blocks, 256, 0, stream>>>(bx, bl, bg, tab, out, N);
}

// Round 7
// 15.750 us; speedup vs baseline: 1.0414x; 1.0414x over previous
//
#include <hip/hip_runtime.h>
#include <math.h>

#define HID 5
#define NTAB 27

__device__ __forceinline__ float sigm(float x) { return 1.0f / (1.0f + expf(-x)); }
__device__ __forceinline__ float softplus_f(float x) {
    return fmaxf(x, 0.0f) + log1pf(expf(-fabsf(x)));
}

__device__ __forceinline__ float sample_out(const float* __restrict__ tab,
                                            float x, float l, float g) {
    int sx = (x > 0.0f) - (x < 0.0f);
    int sl = (l > 0.0f) - (l < 0.0f);
    int sg = (g > 0.0f) - (g < 0.0f);
    float ax = fabsf(x);
    float scale = (ax > 0.0f) ? ax : 1.0f;
    return tab[(sx + 1) * 9 + (sl + 1) * 3 + (sg + 1)] * scale;
}

// Session-best structure (R5, 15.73 us): fused single kernel, input fetch
// pinned above the LUT chain, __launch_bounds__(256,4) so the allocator
// affords the 12 preload VGPRs.
__global__ __launch_bounds__(256, 4) void lstm_opt_v5(
    const float* __restrict__ bx, const float* __restrict__ bl, const float* __restrict__ bg,
    const float* __restrict__ W_ih1, const float* __restrict__ W_hh1,
    const float* __restrict__ b_ih1, const float* __restrict__ b_hh1,
    const float* __restrict__ W_ih2, const float* __restrict__ W_hh2,
    const float* __restrict__ b_ih2, const float* __restrict__ b_hh2,
    const float* __restrict__ W_out, const float* __restrict__ b_out,
    const float* __restrict__ h1_0, const float* __restrict__ c1_0,
    const float* __restrict__ h2_0, const float* __restrict__ c2_0,
    const float* __restrict__ poly, const int* __restrict__ t_ptr,
    float* __restrict__ out, int N)
{
    __shared__ float s_table[32];
    const int tid = threadIdx.x;

    const int gtid = blockIdx.x * blockDim.x + tid;
    const int gstride = gridDim.x * blockDim.x;
    const int nvec = N >> 2;

    const float4* bx4 = reinterpret_cast<const float4*>(bx);
    const float4* bl4 = reinterpret_cast<const float4*>(bl);
    const float4* bg4 = reinterpret_cast<const float4*>(bg);
    float4* out4 = reinterpret_cast<float4*>(out);

    // ---- PHASE 1: issue this thread's entire input fetch (one vec4 triple) ----
    float4 x0, l0, g0;
    bool have0 = (gtid < nvec);
    if (have0) { x0 = bx4[gtid]; l0 = bl4[gtid]; g0 = bg4[gtid]; }
    // Pin the loads above the LUT chain.
    asm volatile("" ::: "memory");

    // ---- PHASE 2: lanes 0..26 of wave 0 compute the LUT while loads fly ----
    if (tid < NTAB) {
        float gn = (float)(tid % 3) - 1.0f;
        float ln = (float)((tid / 3) % 3) - 1.0f;
        float xn = (float)(tid / 9) - 1.0f;

        float h1[HID];
        #pragma unroll
        for (int j = 0; j < HID; ++j) {
            float gk[4];
            #pragma unroll
            for (int q = 0; q < 4; ++q) {
                int k = j + q * HID;
                float acc = b_ih1[k] + b_hh1[k];
                #pragma unroll
                for (int m = 0; m < HID; ++m) acc += W_hh1[k * HID + m] * h1_0[m];
                acc += W_ih1[k * 3 + 0] * xn + W_ih1[k * 3 + 1] * ln + W_ih1[k * 3 + 2] * gn;
                gk[q] = acc;
            }
            float c = sigm(gk[1]) * c1_0[j] + sigm(gk[0]) * tanhf(gk[2]);
            h1[j] = sigm(gk[3]) * tanhf(c);
        }

        float h2v[HID];
        #pragma unroll
        for (int j = 0; j < HID; ++j) {
            float gk[4];
            #pragma unroll
            for (int q = 0; q < 4; ++q) {
                int k = j + q * HID;
                float acc = b_ih2[k] + b_hh2[k];
                #pragma unroll
                for (int m = 0; m < HID; ++m) acc += W_hh2[k * HID + m] * h2_0[m];
                #pragma unroll
                for (int m = 0; m < HID; ++m) acc += W_ih2[k * HID + m] * h1[m];
                gk[q] = acc;
            }
            float c = sigm(gk[1]) * c2_0[j] + sigm(gk[0]) * tanhf(gk[2]);
            h2v[j] = sigm(gk[3]) * tanhf(c);
        }

        float v = b_out[0];
        #pragma unroll
        for (int m = 0; m < HID; ++m) v += W_out[m] * h2v[m];

        int t = *t_ptr;
        float tf = (float)t;
        float pv = 0.0f, p = 1.0f;   // t^0 == 1 even for t==0 (matches Python)
        #pragma unroll
        for (int jj = 0; jj < 4; ++jj) { pv += softplus_f(poly[jj]) * p; p *= tf; }
        float gt = exp2f(tf * -0.0144995696951150f);   // 0.99^t

        s_table[tid] = pv * gt * tanhf(v);
    }
    __syncthreads();

    // ---- PHASE 3: consume the already-loaded data, store ----
    if (have0) {
        float4 o;
        o.x = sample_out(s_table, x0.x, l0.x, g0.x);
        o.y = sample_out(s_table, x0.y, l0.y, g0.y);
        o.z = sample_out(s_table, x0.z, l0.z, g0.z);
        o.w = sample_out(s_table, x0.w, l0.w, g0.w);
        out4[gtid] = o;
    }
    // safety net (no-op when grid covers nvec exactly)
    for (int i = gtid + gstride; i < nvec; i += gstride) {
        float4 x = bx4[i];
        float4 l = bl4[i];
        float4 g = bg4[i];
        float4 o;
        o.x = sample_out(s_table, x.x, l.x, g.x);
        o.y = sample_out(s_table, x.y, l.y, g.y);
        o.z = sample_out(s_table, x.z, l.z, g.z);
        o.w = sample_out(s_table, x.w, l.w, g.w);
        out4[i] = o;
    }
    for (int i = (nvec << 2) + gtid; i < N; i += gstride) {
        out[i] = sample_out(s_table, bx[i], bl[i], bg[i]);
    }
}

extern "C" void kernel_launch(void* const* d_in, const int* in_sizes, int n_in,
                              void* d_out, int out_size, void* d_ws, size_t ws_size,
                              hipStream_t stream) {
    const float* bx    = (const float*)d_in[0];
    const float* bl    = (const float*)d_in[1];
    const float* bg    = (const float*)d_in[2];
    const float* W_ih1 = (const float*)d_in[3];
    const float* W_hh1 = (const float*)d_in[4];
    const float* b_ih1 = (const float*)d_in[5];
    const float* b_hh1 = (const float*)d_in[6];
    const float* W_ih2 = (const float*)d_in[7];
    const float* W_hh2 = (const float*)d_in[8];
    const float* b_ih2 = (const float*)d_in[9];
    const float* b_hh2 = (const float*)d_in[10];
    const float* W_out = (const float*)d_in[11];
    const float* b_out = (const float*)d_in[12];
    const float* h1_0  = (const float*)d_in[13];
    const float* c1_0  = (const float*)d_in[14];
    const float* h2_0  = (const float*)d_in[15];
    const float* c2_0  = (const float*)d_in[16];
    const float* poly  = (const float*)d_in[17];
    const int*   t_ptr = (const int*)d_in[18];
    float* out = (float*)d_out;

    int N = in_sizes[0];
    int nvec = N >> 2;
    int blocks = (nvec + 255) / 256;
    if (blocks < 1) blocks = 1;
    if (blocks > 2048) blocks = 2048;

    lstm_opt_v5<<<blocks, 256, 0, stream>>>(
        bx, bl, bg, W_ih1, W_hh1, b_ih1, b_hh1,
        W_ih2, W_hh2, b_ih2, b_hh2, W_out, b_out,
        h1_0, c1_0, h2_0, c2_0, poly, t_ptr, out, N);
}